// Round 4
// baseline (115.690 us; speedup 1.0000x reference)
//
#include <hip/hip_runtime.h>
#include <float.h>

#define W  128
#define NB 50
#define PROBS_F (NB * NB)   // 2500 floats per series in ws (10000 B, 16B-aligned stride)

// ======================= kernel 1: per-series stats (phases 1-4) =======================
__global__ __launch_bounds__(256) void mtf_stats(const float* __restrict__ X,
                                                 float* __restrict__ wprobs,
                                                 int*   __restrict__ wbins) {
    __shared__ int   bins[W];
    __shared__ int   hist[NB * NB];
    __shared__ int   rowsum[NB];
    __shared__ float redmin[4], redmax[4];

    const int tid = threadIdx.x;
    const int s   = blockIdx.x;
    const float* xrow = X + (size_t)s * W;

    // ---- Phase 1: load + min/max reduction (wave = 64 lanes) ----
    float v = 0.0f;
    float vmin = FLT_MAX, vmax = -FLT_MAX;
    if (tid < W) { v = xrow[tid]; vmin = v; vmax = v; }
    #pragma unroll
    for (int off = 32; off >= 1; off >>= 1) {
        vmin = fminf(vmin, __shfl_down(vmin, off, 64));
        vmax = fmaxf(vmax, __shfl_down(vmax, off, 64));
    }
    if ((tid & 63) == 0) { redmin[tid >> 6] = vmin; redmax[tid >> 6] = vmax; }

    for (int i = tid; i < NB * NB; i += 256) hist[i] = 0;
    if (tid < NB) rowsum[tid] = 0;
    __syncthreads();

    const float mn = fminf(fminf(redmin[0], redmin[1]), fminf(redmin[2], redmin[3]));
    const float mx = fmaxf(fmaxf(redmax[0], redmax[1]), fmaxf(redmax[2], redmax[3]));
    const float d  = (mx - mn) + 1e-6f;   // matches (X_max - X_min + EPS) in fp32

    // ---- Phase 2: bucketize (searchsorted side='left': #{edge < x}) ----
    if (tid < W) {
        float q   = (v - mn) / d;
        float xsc = q * 2.0f - 1.0f;
        double xd = (double)xsc;
        int b = 0;
        #pragma unroll
        for (int k = 1; k <= NB - 1; ++k) {
            double bk = -1.0 + 0.04 * (double)k;   // linspace inner edges (fp64)
            b += (bk < xd) ? 1 : 0;
        }
        bins[tid] = b;
        wbins[(size_t)s * W + tid] = b;            // coalesced 512B row
    }
    __syncthreads();

    // ---- Phase 3: transition histogram + row sums (LDS atomics) ----
    if (tid < W - 1) {
        int bi = bins[tid], bj = bins[tid + 1];
        atomicAdd(&hist[bi * NB + bj], 1);
        atomicAdd(&rowsum[bi], 1);
    }
    __syncthreads();

    // ---- Phase 4: row-normalize, store straight to ws (coalesced) ----
    float* po = wprobs + (size_t)s * PROBS_F;
    for (int i = tid; i < NB * NB; i += 256) {
        int rs = rowsum[i / NB];
        po[i] = (float)hist[i] / (float)(rs == 0 ? 1 : rs);
    }
}

// ======================= kernel 2: pure streaming expand =======================
__global__ __launch_bounds__(256) void mtf_expand(const float* __restrict__ wprobs,
                                                  const int*   __restrict__ wbins,
                                                  float* __restrict__ out) {
    __shared__ __align__(16) float probs[NB * NB];
    __shared__ __align__(16) int   bins[W];

    const int tid = threadIdx.x;
    const int s   = blockIdx.x;

    // Load probs (625 float4s) + bins (32 int4s) — reads are L2/L3-resident (16 MB).
    const float4* ps = (const float4*)(wprobs + (size_t)s * PROBS_F);
    #pragma unroll
    for (int i = tid; i < PROBS_F / 4; i += 256) ((float4*)probs)[i] = ps[i];
    if (tid < W / 4) ((int4*)bins)[tid] = ((const int4*)(wbins + (size_t)s * W))[tid];
    __syncthreads();

    // Gather + contiguous ascending stores (R3 ordering; proven neutral but clean).
    float* orow = out + (size_t)s * W * W;
    const int wv   = tid >> 6;
    const int lane = tid & 63;
    const int c4   = (lane & 31) * 4;
    const int half = lane >> 5;
    const int b0 = bins[c4], b1 = bins[c4 + 1], b2 = bins[c4 + 2], b3 = bins[c4 + 3];
    #pragma unroll
    for (int it = 0; it < 16; ++it) {
        int row = (wv << 5) + (it << 1) + half;
        int rb  = bins[row] * NB;          // LDS broadcast per half-wave
        float4 o;
        o.x = probs[rb + b0];
        o.y = probs[rb + b1];
        o.z = probs[rb + b2];
        o.w = probs[rb + b3];
        *(float4*)(orow + row * W + c4) = o;
    }
}

// ======================= fallback: proven monolithic kernel (R3) =======================
__global__ __launch_bounds__(256) void mtf_kernel(const float* __restrict__ X,
                                                  float* __restrict__ out) {
    __shared__ int   bins[W];
    __shared__ int   hist[NB * NB];
    __shared__ int   rowsum[NB];
    __shared__ float probs[NB * NB];
    __shared__ float redmin[4], redmax[4];

    const int tid = threadIdx.x;
    const int s   = blockIdx.x;
    const float* xrow = X + (size_t)s * W;

    float v = 0.0f;
    float vmin = FLT_MAX, vmax = -FLT_MAX;
    if (tid < W) { v = xrow[tid]; vmin = v; vmax = v; }
    #pragma unroll
    for (int off = 32; off >= 1; off >>= 1) {
        vmin = fminf(vmin, __shfl_down(vmin, off, 64));
        vmax = fmaxf(vmax, __shfl_down(vmax, off, 64));
    }
    if ((tid & 63) == 0) { redmin[tid >> 6] = vmin; redmax[tid >> 6] = vmax; }

    for (int i = tid; i < NB * NB; i += 256) hist[i] = 0;
    if (tid < NB) rowsum[tid] = 0;
    __syncthreads();

    const float mn = fminf(fminf(redmin[0], redmin[1]), fminf(redmin[2], redmin[3]));
    const float mx = fmaxf(fmaxf(redmax[0], redmax[1]), fmaxf(redmax[2], redmax[3]));
    const float d  = (mx - mn) + 1e-6f;

    if (tid < W) {
        float q   = (v - mn) / d;
        float xsc = q * 2.0f - 1.0f;
        double xd = (double)xsc;
        int b = 0;
        #pragma unroll
        for (int k = 1; k <= NB - 1; ++k) {
            double bk = -1.0 + 0.04 * (double)k;
            b += (bk < xd) ? 1 : 0;
        }
        bins[tid] = b;
    }
    __syncthreads();

    if (tid < W - 1) {
        int bi = bins[tid], bj = bins[tid + 1];
        atomicAdd(&hist[bi * NB + bj], 1);
        atomicAdd(&rowsum[bi], 1);
    }
    __syncthreads();

    for (int i = tid; i < NB * NB; i += 256) {
        int rs = rowsum[i / NB];
        probs[i] = (float)hist[i] / (float)(rs == 0 ? 1 : rs);
    }
    __syncthreads();

    float* orow = out + (size_t)s * W * W;
    const int wv   = tid >> 6;
    const int lane = tid & 63;
    const int c4   = (lane & 31) * 4;
    const int half = lane >> 5;
    const int b0 = bins[c4], b1 = bins[c4 + 1], b2 = bins[c4 + 2], b3 = bins[c4 + 3];
    #pragma unroll
    for (int it = 0; it < 16; ++it) {
        int row = (wv << 5) + (it << 1) + half;
        int rb  = bins[row] * NB;
        float4 o;
        o.x = probs[rb + b0];
        o.y = probs[rb + b1];
        o.z = probs[rb + b2];
        o.w = probs[rb + b3];
        *(float4*)(orow + row * W + c4) = o;
    }
}

extern "C" void kernel_launch(void* const* d_in, const int* in_sizes, int n_in,
                              void* d_out, int out_size, void* d_ws, size_t ws_size,
                              hipStream_t stream) {
    const float* X = (const float*)d_in[0];
    float* out = (float*)d_out;
    int S = in_sizes[0] / W;                       // 256*6 = 1536 series

    const size_t probs_bytes = (size_t)S * PROBS_F * sizeof(float);   // 15.36 MB
    const size_t bins_bytes  = (size_t)S * W * sizeof(int);           //  0.79 MB

    if (d_ws && ws_size >= probs_bytes + bins_bytes) {
        float* wprobs = (float*)d_ws;
        int*   wbins  = (int*)((char*)d_ws + probs_bytes);            // 16B-aligned offset
        mtf_stats <<<dim3(S), dim3(256), 0, stream>>>(X, wprobs, wbins);
        mtf_expand<<<dim3(S), dim3(256), 0, stream>>>(wprobs, wbins, out);
    } else {
        mtf_kernel<<<dim3(S), dim3(256), 0, stream>>>(X, out);        // proven fallback
    }
}